// Round 14
// baseline (384.576 us; speedup 1.0000x reference)
//
#include <hip/hip_runtime.h>

#define NN 50000
#define NE 800000

typedef _Float16 half8 __attribute__((ext_vector_type(8)));
typedef _Float16 half4 __attribute__((ext_vector_type(4)));
typedef float f32x4 __attribute__((ext_vector_type(4)));
typedef unsigned long long u64;

// ws layout (float offsets)
static const size_t XHOFF  = 0;          // xh     [50000*64] f16
static const size_t POFF   = 3200000;    // P(+b1) [50000*128] f16 (k-permuted)
static const size_t QOFF   = 6400000;    // Q      [50000*128] f16 (k-permuted)
static const size_t N1OFF  = 9600000;    // nfoc1  [50000*64] f32
static const size_t N2OFF  = 12800000;   // nfoc2  [50000*64] u32 (monotonic-encoded)
static const size_t W2TOFF = 16000000;   // w2t    [128c][128k'] f16 (col-major, k-perm)
static const size_t WGHOFF = 16008192;   // w2gh   [128] f16 (k-perm)
static const size_t RW1HOFF= 16008256;   // rw1h   [64c][64k] f16
static const size_t RW2HOFF= 16010304;   // rw2h   [64c][64k] f16
static const size_t L1WHOFF= 16012352;   // l1wh   [64c][64k] f16
static const size_t PWHOFF = 16014400;   // pwh    [128c][64k] f16
static const size_t QWHOFF = 16018496;   // qwh    [128c][64k] f16
static const size_t CNTOFF = 16022592;   // counts [50000] u32
static const size_t CUROFF = 16072592;   // cursor [50000] u32
static const size_t PARTOFF= 16122592;   // partial[256] u32
static const size_t SDOFF  = 16122848;   // sdbuf  [800000] u64
static const size_t FWOFF  = 17722848;   // fwh    [64c][192k] f16 (fused red@l2)
static const size_t FBOFF  = 17729200;   // fb     [64] f32

__device__ __forceinline__ unsigned fenc(float f){
  unsigned b = __float_as_uint(f);
  return (b & 0x80000000u) ? ~b : (b | 0x80000000u);
}
__device__ __forceinline__ float fdec(unsigned u){
  return (u & 0x80000000u) ? __uint_as_float(u & 0x7fffffffu) : __uint_as_float(~u);
}

// k-permutation: k' = kg*32 + kt*4 + j  <->  k = kt*16 + kg*4 + j
__device__ __forceinline__ int kperm(int kp){
  const int kg = kp >> 5, rem = kp & 31, kt = rem >> 2, j = rem & 3;
  return kt*16 + kg*4 + j;
}

// blocks 0..176: weight relayouts/conversions.
// blocks 177..184: fused W' = red_w @ l2w (parallel, LDS-staged).
// blocks 185+: dst histogram (counts pre-zeroed by memset).
__global__ __launch_bounds__(256) void prep_k(
    const float* __restrict__ w2, const float* __restrict__ rw1,
    const float* __restrict__ rw2, const float* __restrict__ l1w,
    const float* __restrict__ mw1,
    const float* __restrict__ redw, const float* __restrict__ redb,
    const float* __restrict__ l2w, const float* __restrict__ l2b,
    _Float16* __restrict__ w2t, _Float16* __restrict__ w2gh,
    _Float16* __restrict__ rw1h, _Float16* __restrict__ rw2h,
    _Float16* __restrict__ l1wh, _Float16* __restrict__ pwh,
    _Float16* __restrict__ qwh,
    _Float16* __restrict__ fwh, float* __restrict__ fb,
    const int* __restrict__ dst, unsigned* __restrict__ counts)
{
  __shared__ float sl2[64][8];
  const int b = blockIdx.x;
  if (b < 177){
    int i = b * 256 + threadIdx.x;
    if (i < 16384){
      int c = i >> 7, kp = i & 127;
      w2t[i] = (_Float16)w2[kperm(kp)*129 + 1 + c];
    } else if (i < 16512){
      int kp = i - 16384;
      w2gh[kp] = (_Float16)w2[kperm(kp)*129];
    } else if (i < 20608){
      int idx = i - 16512, c = idx >> 6, k = idx & 63;
      rw1h[idx] = (_Float16)rw1[k*64 + c];
    } else if (i < 24704){
      int idx = i - 20608, c = idx >> 6, k = idx & 63;
      rw2h[idx] = (_Float16)rw2[k*64 + c];
    } else if (i < 28800){
      int idx = i - 24704, c = idx >> 6, k = idx & 63;
      l1wh[idx] = (_Float16)l1w[k*64 + c];
    } else if (i < 36992){
      int idx = i - 28800, c = idx >> 6, k = idx & 63;
      pwh[idx] = (_Float16)mw1[k*128 + c];
    } else if (i < 45184){
      int idx = i - 36992, c = idx >> 6, k = idx & 63;
      qwh[idx] = (_Float16)mw1[(64 + k)*128 + c];
    }
  } else if (b < 185){
    const int b2 = b - 177;
    const int c0 = b2 * 8;
    const int t = threadIdx.x;
    #pragma unroll
    for (int i = 0; i < 2; ++i){
      int idx = t + i*256;
      int j = idx >> 3, cc = idx & 7;
      sl2[j][cc] = l2w[j*64 + c0 + cc];
    }
    __syncthreads();
    for (int o = t; o < 1536; o += 256){
      int k = o >> 3, cc = o & 7;
      const float4* rw = (const float4*)&redw[k*64];
      float a = 0.f;
      #pragma unroll
      for (int q = 0; q < 16; ++q){
        const float4 r4 = rw[q];
        a = fmaf(r4.x, sl2[q*4+0][cc], a);
        a = fmaf(r4.y, sl2[q*4+1][cc], a);
        a = fmaf(r4.z, sl2[q*4+2][cc], a);
        a = fmaf(r4.w, sl2[q*4+3][cc], a);
      }
      fwh[(size_t)(c0 + cc)*192 + k] = (_Float16)a;
    }
    if (t < 8){
      float a = l2b[c0 + t];
      #pragma unroll 8
      for (int j = 0; j < 64; ++j) a = fmaf(redb[j], sl2[j][t], a);
      fb[c0 + t] = a;
    }
  } else {
    int e = (b - 185) * 256 + threadIdx.x;
    if (e < NE) atomicAdd(&counts[dst[e]], 1u);
  }
}

// blocks 0..195: per-block sums of counts -> partial. blocks 196+: zero nfoc1/nfoc2.
__global__ __launch_bounds__(256) void scanA2(const unsigned* __restrict__ counts,
                                              unsigned* __restrict__ partial,
                                              uint4* __restrict__ nfz)
{
  __shared__ unsigned s[256];
  const int b = blockIdx.x;
  const int t = threadIdx.x;
  if (b < 196){
    const int idx = b * 256 + t;
    s[t] = (idx < NN) ? counts[idx] : 0u;
    __syncthreads();
    for (int d = 128; d > 0; d >>= 1){
      if (t < d) s[t] += s[t + d];
      __syncthreads();
    }
    if (t == 0) partial[b] = s[0];
  } else {
    const size_t i0 = ((size_t)(b - 196) * 256 + t) * 4;
    #pragma unroll
    for (int i = 0; i < 4; ++i){
      const size_t idx = i0 + i;
      if (idx < 1600000) nfz[idx] = make_uint4(0u,0u,0u,0u);
    }
  }
}

// block-local exclusive scan + inline prefix of partial[0..bid) -> cursor
__global__ __launch_bounds__(256) void scanC2(const unsigned* __restrict__ counts,
                                              const unsigned* __restrict__ partial,
                                              unsigned* __restrict__ cursor)
{
  __shared__ unsigned sp[256];
  __shared__ unsigned s[256];
  const int t = threadIdx.x;
  const int b = blockIdx.x;
  sp[t] = (t < 196 && t < b) ? partial[t] : 0u;
  __syncthreads();
  for (int d = 128; d > 0; d >>= 1){
    if (t < d) sp[t] += sp[t + d];
    __syncthreads();
  }
  const unsigned boff = sp[0];
  const int idx = b * 256 + t;
  unsigned v = (idx < NN) ? counts[idx] : 0u;
  s[t] = v;
  __syncthreads();
  for (int d = 1; d < 256; d <<= 1){
    unsigned u = (t >= d) ? s[t - d] : 0u;
    __syncthreads();
    s[t] += u;
    __syncthreads();
  }
  if (idx < NN) cursor[idx] = boff + s[t] - v;
}

// combo: blocks 0..3124 = slot assignment; blocks 3125..3906 = node_pre (MFMA).
__global__ __launch_bounds__(256) void combo_k(
    const int* __restrict__ src, const int* __restrict__ dst,
    unsigned* __restrict__ cursor, u64* __restrict__ sdbuf,
    const float* __restrict__ nf,
    const _Float16* __restrict__ rw1h, const float* __restrict__ rb1,
    const _Float16* __restrict__ rw2h, const float* __restrict__ rb2,
    const _Float16* __restrict__ l1wh, const float* __restrict__ l1b,
    const _Float16* __restrict__ pwh, const _Float16* __restrict__ qwh,
    const float* __restrict__ mb1,
    _Float16* __restrict__ xh, _Float16* __restrict__ Pp, _Float16* __restrict__ Qp,
    float* __restrict__ out)
{
  __shared__ _Float16 sM[64][72];
  __shared__ _Float16 sT[64][72];
  const int b = blockIdx.x;
  const int t = threadIdx.x;

  if (b < 3125){
    int e = b * 256 + t;
    if (e < NE){
      const int d = dst[e];
      unsigned slot = atomicAdd(&cursor[d], 1u);
      sdbuf[slot] = ((u64)(unsigned)d << 32) | (unsigned)src[e];
    }
    return;
  }

  const int lane = t & 63, wv = t >> 6;
  const int l15 = lane & 15, kg = lane >> 4;
  const int n0 = (b - 3125) * 64;

  {
    const int rr = t >> 4, c4 = (t & 15) * 4;
    #pragma unroll
    for (int i = 0; i < 4; ++i){
      int r = rr + i*16, n = n0 + r;
      float4 v = make_float4(0.f,0.f,0.f,0.f);
      if (n < NN) v = *(const float4*)&nf[(size_t)n*64 + c4];
      half4 h; h[0]=(_Float16)v.x; h[1]=(_Float16)v.y; h[2]=(_Float16)v.z; h[3]=(_Float16)v.w;
      *(half4*)&sM[r][c4] = h;
    }
  }
  __syncthreads();

  const int col = wv*16 + l15;

  // GEMM1: tmp = nf@rw1 + rb1 -> sT
  {
    half4 bf[4];
    #pragma unroll
    for (int kt = 0; kt < 4; ++kt) bf[kt] = *(const half4*)&rw1h[col*64 + kt*16 + kg*4];
    const float bias = rb1[col];
    #pragma unroll
    for (int rt = 0; rt < 4; ++rt){
      f32x4 acc = {0.f,0.f,0.f,0.f};
      #pragma unroll
      for (int kt = 0; kt < 4; ++kt){
        const half4 af = *(const half4*)&sM[rt*16 + l15][kt*16 + kg*4];
        acc = __builtin_amdgcn_mfma_f32_16x16x16f16(af, bf[kt], acc, 0, 0, 0);
      }
      #pragma unroll
      for (int reg = 0; reg < 4; ++reg)
        sT[rt*16 + kg*4 + reg][col] = (_Float16)(acc[reg] + bias);
    }
  }
  __syncthreads();

  // GEMM2: x = tmp@rw2 + rb2 + nf -> xh (f16) and sM (in-place, lane-owned)
  {
    half4 bf[4];
    #pragma unroll
    for (int kt = 0; kt < 4; ++kt) bf[kt] = *(const half4*)&rw2h[col*64 + kt*16 + kg*4];
    const float bias = rb2[col];
    #pragma unroll
    for (int rt = 0; rt < 4; ++rt){
      f32x4 acc = {0.f,0.f,0.f,0.f};
      #pragma unroll
      for (int kt = 0; kt < 4; ++kt){
        const half4 af = *(const half4*)&sT[rt*16 + l15][kt*16 + kg*4];
        acc = __builtin_amdgcn_mfma_f32_16x16x16f16(af, bf[kt], acc, 0, 0, 0);
      }
      #pragma unroll
      for (int reg = 0; reg < 4; ++reg){
        const int row = rt*16 + kg*4 + reg;
        const float xv = acc[reg] + bias + (float)sM[row][col];
        const _Float16 xvh = (_Float16)xv;
        const int n = n0 + row;
        if (n < NN) xh[(size_t)n*64 + col] = xvh;
        sM[row][col] = xvh;
      }
    }
  }
  __syncthreads();

  // GEMM3: x1 = x@l1w + l1b -> out
  {
    half4 bf[4];
    #pragma unroll
    for (int kt = 0; kt < 4; ++kt) bf[kt] = *(const half4*)&l1wh[col*64 + kt*16 + kg*4];
    const float bias = l1b[col];
    #pragma unroll
    for (int rt = 0; rt < 4; ++rt){
      f32x4 acc = {0.f,0.f,0.f,0.f};
      #pragma unroll
      for (int kt = 0; kt < 4; ++kt){
        const half4 af = *(const half4*)&sM[rt*16 + l15][kt*16 + kg*4];
        acc = __builtin_amdgcn_mfma_f32_16x16x16f16(af, bf[kt], acc, 0, 0, 0);
      }
      #pragma unroll
      for (int reg = 0; reg < 4; ++reg){
        const int row = rt*16 + kg*4 + reg;
        const int n = n0 + row;
        if (n < NN) out[(size_t)n*64 + col] = acc[reg] + bias;
      }
    }
  }

  // GEMM4/5: P = x@W1top + b1 (folded), Q = x@W1bot; k-permuted stores
  #pragma unroll
  for (int g = 0; g < 2; ++g){
    const _Float16* WH = g ? qwh : pwh;
    _Float16* dstp = g ? Qp : Pp;
    #pragma unroll
    for (int h = 0; h < 2; ++h){
      const int ct = h*4 + wv;
      const int colp = ct*16 + l15;
      half4 bf[4];
      #pragma unroll
      for (int kt = 0; kt < 4; ++kt) bf[kt] = *(const half4*)&WH[colp*64 + kt*16 + kg*4];
      const float bias = g ? 0.f : mb1[colp];
      const int kgc = l15 >> 2, jj = l15 & 3;
      const int pos = kgc*32 + ct*4 + jj;   // kperm(pos) == colp
      #pragma unroll
      for (int rt = 0; rt < 4; ++rt){
        f32x4 acc = {0.f,0.f,0.f,0.f};
        #pragma unroll
        for (int kt = 0; kt < 4; ++kt){
          const half4 af = *(const half4*)&sM[rt*16 + l15][kt*16 + kg*4];
          acc = __builtin_amdgcn_mfma_f32_16x16x16f16(af, bf[kt], acc, 0, 0, 0);
        }
        #pragma unroll
        for (int reg = 0; reg < 4; ++reg){
          const int row = rt*16 + kg*4 + reg;
          const int n = n0 + row;
          if (n < NN) dstp[(size_t)n*128 + pos] = (_Float16)(acc[reg] + bias);
        }
      }
    }
  }
}

// Edge MLP v9: 10 tiles/block, sd prefetched 2 tiles ahead (index chain decoupled
// from gather), P/Q gather 1 tile ahead, B + gate weights hoisted. 1250 blocks.
__global__ __launch_bounds__(256) void edge_mlp9(
    const u64* __restrict__ sd,
    const _Float16* __restrict__ Pp, const _Float16* __restrict__ Qp,
    const _Float16* __restrict__ w2t, const _Float16* __restrict__ w2gh,
    const float* __restrict__ b2,
    float* __restrict__ nfoc1, unsigned* __restrict__ nfoc2)
{
  __shared__ _Float16 sA[64][136];
  __shared__ _Float16 sOutH[64][136];
  __shared__ float sK[2][64];
  __shared__ int   sD[2][64];
  const int t = threadIdx.x;
  const int lane = t & 63, wv = t >> 6;
  const int r  = lane & 15;
  const int kg = lane >> 4;
  const int row0 = wv * 16;
  const int base = blockIdx.x * 640;   // 10 tiles x 64 edges

  // issue sd loads for tiles 0,1 immediately (latency hides under bf hoist)
  u64 sdC = sd[base + row0 + r];
  u64 sdN = sd[base + 64 + row0 + r];

  // hoist B-fragments (2 col-tiles) + gate weights
  const int ct0 = wv * 2;
  half4 bf0[8], bf1[8];
  half8 wgr[4];
  float bias0, bias1;
  {
    const int col0 = ct0*16 + r, col1 = (ct0+1)*16 + r;
    bias0 = b2[1 + col0]; bias1 = b2[1 + col1];
    const _Float16* w0p = &w2t[(size_t)col0*128 + kg*32];
    const _Float16* w1p = &w2t[(size_t)col1*128 + kg*32];
    #pragma unroll
    for (int kt = 0; kt < 8; ++kt){
      bf0[kt] = *(const half4*)&w0p[kt*4];
      bf1[kt] = *(const half4*)&w1p[kt*4];
    }
    #pragma unroll
    for (int i = 0; i < 4; ++i) wgr[i] = *(const half8*)&w2gh[kg*32 + i*8];
  }
  const float gb = b2[0];

#define GATHER(PH, QH, DD, SDV) { \
    const int ss_ = (int)(unsigned)((SDV) & 0xffffffffu); \
    DD = (int)(unsigned)((SDV) >> 32); \
    const _Float16* pr = &Pp[(size_t)ss_ * 128 + kg*32]; \
    const _Float16* qr = &Qp[(size_t)DD * 128 + kg*32]; \
    PH[0] = *(const half8*)&pr[0];  PH[1] = *(const half8*)&pr[8]; \
    PH[2] = *(const half8*)&pr[16]; PH[3] = *(const half8*)&pr[24]; \
    QH[0] = *(const half8*)&qr[0];  QH[1] = *(const half8*)&qr[8]; \
    QH[2] = *(const half8*)&qr[16]; QH[3] = *(const half8*)&qr[24]; }

#define PROCESS(PH, QH, DD, BUF) { \
    if (kg == 0) sD[BUF][row0 + r] = DD; \
    float gp = 0.f; \
    _Pragma("unroll") \
    for (int i = 0; i < 4; ++i){ \
      half8 mv = PH[i] + QH[i]; \
      const half8 m2 = mv * (_Float16)0.2f; \
      mv = __builtin_elementwise_max(mv, m2); \
      _Pragma("unroll") \
      for (int j = 0; j < 8; ++j) \
        gp = fmaf((float)mv[j], (float)wgr[i][j], gp); \
      *(half8*)&sA[row0 + r][kg*32 + i*8] = mv; \
    } \
    gp += __shfl_xor(gp, 16); \
    gp += __shfl_xor(gp, 32); \
    if (kg == 0) sK[BUF][row0 + r] = 1.f / (1.f + expf(-(gp + gb))); }

#define COMPUTE() { \
    _Pragma("unroll") \
    for (int rt = 0; rt < 4; ++rt){ \
      half4 af[8]; \
      const _Float16* ar = &sA[rt*16 + r][kg*32]; \
      _Pragma("unroll") \
      for (int kt = 0; kt < 8; ++kt) af[kt] = *(const half4*)&ar[kt*4]; \
      f32x4 a0 = {0.f,0.f,0.f,0.f}, a1 = {0.f,0.f,0.f,0.f}; \
      _Pragma("unroll") \
      for (int kt = 0; kt < 8; ++kt){ \
        a0 = __builtin_amdgcn_mfma_f32_16x16x16f16(af[kt], bf0[kt], a0, 0, 0, 0); \
        a1 = __builtin_amdgcn_mfma_f32_16x16x16f16(af[kt], bf1[kt], a1, 0, 0, 0); \
      } \
      _Pragma("unroll") \
      for (int reg = 0; reg < 4; ++reg){ \
        const int row = rt*16 + kg*4 + reg; \
        sOutH[row][ ct0   *16 + r] = (_Float16)(a0[reg] + bias0); \
        sOutH[row][(ct0+1)*16 + r] = (_Float16)(a1[reg] + bias1); \
      } \
    } }

#define REDUCE(BUF) { \
    const int c = t & 127; \
    const int rbeg = (t >> 7) * 32; \
    const bool isSum = c < 64; \
    float acc = isSum ? 0.f : -1e30f; \
    int curd = sD[BUF][rbeg]; \
    _Pragma("unroll 4") \
    for (int rw = rbeg; rw < rbeg + 32; ++rw){ \
      const float v = (float)sOutH[rw][c] * sK[BUF][rw]; \
      acc = isSum ? (acc + v) : fmaxf(acc, v); \
      const bool last = (rw == rbeg + 31) || (sD[BUF][rw + 1] != curd); \
      if (last){ \
        if (isSum){ \
          unsafeAtomicAdd(&nfoc1[(size_t)curd*64 + c], acc); \
          acc = 0.f; \
        } else { \
          atomicMax(&nfoc2[(size_t)curd*64 + (c - 64)], fenc(acc)); \
          acc = -1e30f; \
        } \
        if (rw < rbeg + 31) curd = sD[BUF][rw + 1]; \
      } \
    } }

  int dA, dB;
  half8 phA[4], qhA[4], phB[4], qhB[4];

  GATHER(phA, qhA, dA, sdC);

  #pragma unroll
  for (int tl = 0; tl < 10; ++tl){
    // issue sd load for tile tl+2 (consumed by GATHER one full tile later)
    u64 sdNN = 0;
    if (tl < 8) sdNN = sd[base + (tl + 2)*64 + row0 + r];

    if ((tl & 1) == 0){
      if (tl < 9) GATHER(phB, qhB, dB, sdN);
      PROCESS(phA, qhA, dA, 0);
    } else {
      if (tl < 9) GATHER(phA, qhA, dA, sdN);
      PROCESS(phB, qhB, dB, 1);
    }
    __syncthreads();
    COMPUTE();
    __syncthreads();
    if ((tl & 1) == 0){ REDUCE(0); } else { REDUCE(1); }

    sdN = sdNN;
  }

#undef GATHER
#undef PROCESS
#undef COMPUTE
#undef REDUCE
}

// Node-side post (MFMA, fused weight): out += concat(x,nfoc1,nfoc2) @ W' + fb
__global__ __launch_bounds__(256) void node_post_m(
    const _Float16* __restrict__ xh, const float* __restrict__ nfoc1,
    const unsigned* __restrict__ nfoc2, const unsigned* __restrict__ counts,
    const _Float16* __restrict__ fwh, const float* __restrict__ fb,
    float* __restrict__ out)
{
  __shared__ _Float16 sC[64][200];
  const int t = threadIdx.x;
  const int lane = t & 63, wv = t >> 6;
  const int l15 = lane & 15, kg = lane >> 4;
  const int n0 = blockIdx.x * 64;

  {
    const int rr = t >> 4, c4 = (t & 15) * 4;
    #pragma unroll
    for (int i = 0; i < 4; ++i){
      int r = rr + i*16, n = n0 + r;
      half4 xv = {};
      float4 f1 = make_float4(0,0,0,0);
      uint4 f2 = make_uint4(0,0,0,0);
      bool has = false;
      if (n < NN){
        xv = *(const half4*)&xh[(size_t)n*64 + c4];
        f1 = *(const float4*)&nfoc1[(size_t)n*64 + c4];
        f2 = *(const uint4*)&nfoc2[(size_t)n*64 + c4];
        has = counts[n] > 0u;
      }
      *(half4*)&sC[r][c4] = xv;
      half4 h1; h1[0]=(_Float16)f1.x; h1[1]=(_Float16)f1.y; h1[2]=(_Float16)f1.z; h1[3]=(_Float16)f1.w;
      *(half4*)&sC[r][64 + c4] = h1;
      half4 h2;
      h2[0] = has ? (_Float16)fdec(f2.x) : (_Float16)0.f;
      h2[1] = has ? (_Float16)fdec(f2.y) : (_Float16)0.f;
      h2[2] = has ? (_Float16)fdec(f2.z) : (_Float16)0.f;
      h2[3] = has ? (_Float16)fdec(f2.w) : (_Float16)0.f;
      *(half4*)&sC[r][128 + c4] = h2;
    }
  }
  __syncthreads();

  const int col = wv*16 + l15;
  half4 bf[12];
  #pragma unroll
  for (int kt = 0; kt < 12; ++kt) bf[kt] = *(const half4*)&fwh[col*192 + kt*16 + kg*4];
  const float bias = fb[col];

  #pragma unroll
  for (int rt = 0; rt < 4; ++rt){
    f32x4 acc = {0.f,0.f,0.f,0.f};
    #pragma unroll
    for (int kt = 0; kt < 12; ++kt){
      const half4 af = *(const half4*)&sC[rt*16 + l15][kt*16 + kg*4];
      acc = __builtin_amdgcn_mfma_f32_16x16x16f16(af, bf[kt], acc, 0, 0, 0);
    }
    #pragma unroll
    for (int reg = 0; reg < 4; ++reg){
      const int row = rt*16 + kg*4 + reg;
      const int n = n0 + row;
      if (n < NN) out[(size_t)n*64 + col] += acc[reg] + bias;
    }
  }
}

extern "C" void kernel_launch(void* const* d_in, const int* in_sizes, int n_in,
                              void* d_out, int out_size, void* d_ws, size_t ws_size,
                              hipStream_t stream)
{
  const float* nf   = (const float*)d_in[0];
  const int*   src  = (const int*)d_in[1];
  const int*   dst  = (const int*)d_in[2];
  const float* rw1  = (const float*)d_in[3];
  const float* rb1  = (const float*)d_in[4];
  const float* rw2  = (const float*)d_in[5];
  const float* rb2  = (const float*)d_in[6];
  const float* l1w  = (const float*)d_in[7];
  const float* l1b  = (const float*)d_in[8];
  const float* l2w  = (const float*)d_in[9];
  const float* l2b  = (const float*)d_in[10];
  const float* mw1  = (const float*)d_in[11];
  const float* mb1  = (const float*)d_in[12];
  const float* mw2  = (const float*)d_in[13];
  const float* mb2  = (const float*)d_in[14];
  const float* redw = (const float*)d_in[15];
  const float* redb = (const float*)d_in[16];

  float* ws = (float*)d_ws;
  _Float16*  xh     = (_Float16*)(ws + XHOFF);
  _Float16*  P      = (_Float16*)(ws + POFF);
  _Float16*  Q      = (_Float16*)(ws + QOFF);
  float*     nfoc1  = ws + N1OFF;
  unsigned*  nfoc2  = (unsigned*)(ws + N2OFF);
  _Float16*  w2t    = (_Float16*)(ws + W2TOFF);
  _Float16*  w2gh   = (_Float16*)(ws + WGHOFF);
  _Float16*  rw1h   = (_Float16*)(ws + RW1HOFF);
  _Float16*  rw2h   = (_Float16*)(ws + RW2HOFF);
  _Float16*  l1wh   = (_Float16*)(ws + L1WHOFF);
  _Float16*  pwh    = (_Float16*)(ws + PWHOFF);
  _Float16*  qwh    = (_Float16*)(ws + QWHOFF);
  unsigned*  counts = (unsigned*)(ws + CNTOFF);
  unsigned*  cursor = (unsigned*)(ws + CUROFF);
  unsigned*  partial= (unsigned*)(ws + PARTOFF);
  u64*       sdbuf  = (u64*)(ws + SDOFF);
  _Float16*  fwh    = (_Float16*)(ws + FWOFF);
  float*     fb     = ws + FBOFF;
  float*     out    = (float*)d_out;

  hipMemsetAsync(counts, 0, NN * sizeof(unsigned), stream);
  hipLaunchKernelGGL(prep_k, dim3(185 + 3125), dim3(256), 0, stream,
                     mw2, rw1, rw2, l1w, mw1, redw, redb, l2w, l2b,
                     w2t, w2gh, rw1h, rw2h, l1wh, pwh, qwh, fwh, fb, dst, counts);
  hipLaunchKernelGGL(scanA2, dim3(196 + 1563), dim3(256), 0, stream,
                     counts, partial, (uint4*)nfoc1);
  hipLaunchKernelGGL(scanC2, dim3(196), dim3(256), 0, stream, counts, partial, cursor);
  hipLaunchKernelGGL(combo_k, dim3(3125 + 782), dim3(256), 0, stream,
                     src, dst, cursor, sdbuf,
                     nf, rw1h, rb1, rw2h, rb2, l1wh, l1b, pwh, qwh, mb1,
                     xh, P, Q, out);
  hipLaunchKernelGGL(edge_mlp9, dim3(1250), dim3(256), 0, stream,
                     sdbuf, P, Q, w2t, w2gh, mb2, nfoc1, nfoc2);
  hipLaunchKernelGGL(node_post_m, dim3(782), dim3(256), 0, stream,
                     xh, nfoc1, nfoc2, counts, fwh, fb, out);
}

// Round 15
// 278.201 us; speedup vs baseline: 1.3824x; 1.3824x over previous
//
#include <hip/hip_runtime.h>

#define NN 50000
#define NE 800000

typedef _Float16 half8 __attribute__((ext_vector_type(8)));
typedef _Float16 half4 __attribute__((ext_vector_type(4)));
typedef float f32x4 __attribute__((ext_vector_type(4)));
typedef unsigned long long u64;

// ws layout (float offsets)
static const size_t XHOFF  = 0;          // xh     [50000*64] f16
static const size_t POFF   = 3200000;    // P(+b1) [50000*128] f16 (k-permuted)
static const size_t QOFF   = 6400000;    // Q      [50000*128] f16 (k-permuted)
static const size_t N1OFF  = 9600000;    // nfoc1  [50000*64] f32
static const size_t N2OFF  = 12800000;   // nfoc2  [50000*64] u32 (monotonic-encoded)
static const size_t W2TOFF = 16000000;   // w2t    [128c][128k'] f16 (col-major, k-perm)
static const size_t WGHOFF = 16008192;   // w2gh   [128] f16 (k-perm)
static const size_t RW1HOFF= 16008256;   // rw1h   [64c][64k] f16
static const size_t RW2HOFF= 16010304;   // rw2h   [64c][64k] f16
static const size_t L1WHOFF= 16012352;   // l1wh   [64c][64k] f16
static const size_t PWHOFF = 16014400;   // pwh    [128c][64k] f16
static const size_t QWHOFF = 16018496;   // qwh    [128c][64k] f16
static const size_t CNTOFF = 16022592;   // counts [50000] u32
static const size_t CUROFF = 16072592;   // cursor [50000] u32
static const size_t PARTOFF= 16122592;   // partial[256] u32
static const size_t SDOFF  = 16122848;   // sdbuf  [800000] u64
static const size_t FWOFF  = 17722848;   // fwh    [64c][192k] f16 (fused red@l2)
static const size_t FBOFF  = 17729200;   // fb     [64] f32

__device__ __forceinline__ unsigned fenc(float f){
  unsigned b = __float_as_uint(f);
  return (b & 0x80000000u) ? ~b : (b | 0x80000000u);
}
__device__ __forceinline__ float fdec(unsigned u){
  return (u & 0x80000000u) ? __uint_as_float(u & 0x7fffffffu) : __uint_as_float(~u);
}

// k-permutation: k' = kg*32 + kt*4 + j  <->  k = kt*16 + kg*4 + j
__device__ __forceinline__ int kperm(int kp){
  const int kg = kp >> 5, rem = kp & 31, kt = rem >> 2, j = rem & 3;
  return kt*16 + kg*4 + j;
}

// blocks 0..176: weight relayouts. 177..184: fused W' = red_w@l2w.
// 185..1747: zero nfoc1/nfoc2. 1748+: dst histogram (counts pre-zeroed).
__global__ __launch_bounds__(256) void prep_k(
    const float* __restrict__ w2, const float* __restrict__ rw1,
    const float* __restrict__ rw2, const float* __restrict__ l1w,
    const float* __restrict__ mw1,
    const float* __restrict__ redw, const float* __restrict__ redb,
    const float* __restrict__ l2w, const float* __restrict__ l2b,
    _Float16* __restrict__ w2t, _Float16* __restrict__ w2gh,
    _Float16* __restrict__ rw1h, _Float16* __restrict__ rw2h,
    _Float16* __restrict__ l1wh, _Float16* __restrict__ pwh,
    _Float16* __restrict__ qwh,
    _Float16* __restrict__ fwh, float* __restrict__ fb,
    uint4* __restrict__ nfz,
    const int* __restrict__ dst, unsigned* __restrict__ counts)
{
  __shared__ float sl2[64][8];
  const int b = blockIdx.x;
  if (b < 177){
    int i = b * 256 + threadIdx.x;
    if (i < 16384){
      int c = i >> 7, kp = i & 127;
      w2t[i] = (_Float16)w2[kperm(kp)*129 + 1 + c];
    } else if (i < 16512){
      int kp = i - 16384;
      w2gh[kp] = (_Float16)w2[kperm(kp)*129];
    } else if (i < 20608){
      int idx = i - 16512, c = idx >> 6, k = idx & 63;
      rw1h[idx] = (_Float16)rw1[k*64 + c];
    } else if (i < 24704){
      int idx = i - 20608, c = idx >> 6, k = idx & 63;
      rw2h[idx] = (_Float16)rw2[k*64 + c];
    } else if (i < 28800){
      int idx = i - 24704, c = idx >> 6, k = idx & 63;
      l1wh[idx] = (_Float16)l1w[k*64 + c];
    } else if (i < 36992){
      int idx = i - 28800, c = idx >> 6, k = idx & 63;
      pwh[idx] = (_Float16)mw1[k*128 + c];
    } else if (i < 45184){
      int idx = i - 36992, c = idx >> 6, k = idx & 63;
      qwh[idx] = (_Float16)mw1[(64 + k)*128 + c];
    }
  } else if (b < 185){
    const int b2 = b - 177;
    const int c0 = b2 * 8;
    const int t = threadIdx.x;
    #pragma unroll
    for (int i = 0; i < 2; ++i){
      int idx = t + i*256;
      int j = idx >> 3, cc = idx & 7;
      sl2[j][cc] = l2w[j*64 + c0 + cc];
    }
    __syncthreads();
    for (int o = t; o < 1536; o += 256){
      int k = o >> 3, cc = o & 7;
      const float4* rw = (const float4*)&redw[k*64];
      float a = 0.f;
      #pragma unroll
      for (int q = 0; q < 16; ++q){
        const float4 r4 = rw[q];
        a = fmaf(r4.x, sl2[q*4+0][cc], a);
        a = fmaf(r4.y, sl2[q*4+1][cc], a);
        a = fmaf(r4.z, sl2[q*4+2][cc], a);
        a = fmaf(r4.w, sl2[q*4+3][cc], a);
      }
      fwh[(size_t)(c0 + cc)*192 + k] = (_Float16)a;
    }
    if (t < 8){
      float a = l2b[c0 + t];
      #pragma unroll 8
      for (int j = 0; j < 64; ++j) a = fmaf(redb[j], sl2[j][t], a);
      fb[c0 + t] = a;
    }
  } else if (b < 1748){
    // zero nfoc1+nfoc2: 25.6MB = 1.6M uint4 (overlaps histogram blocks)
    const size_t i0 = ((size_t)(b - 185) * 256 + threadIdx.x) * 4;
    #pragma unroll
    for (int i = 0; i < 4; ++i){
      const size_t idx = i0 + i;
      if (idx < 1600000) nfz[idx] = make_uint4(0u,0u,0u,0u);
    }
  } else {
    int e = (b - 1748) * 256 + threadIdx.x;
    if (e < NE) atomicAdd(&counts[dst[e]], 1u);
  }
}

// per-block sums of counts -> partial[196]
__global__ __launch_bounds__(256) void scanA(const unsigned* __restrict__ counts,
                                             unsigned* __restrict__ partial)
{
  __shared__ unsigned s[256];
  const int t = threadIdx.x;
  const int idx = blockIdx.x * 256 + t;
  s[t] = (idx < NN) ? counts[idx] : 0u;
  __syncthreads();
  for (int d = 128; d > 0; d >>= 1){
    if (t < d) s[t] += s[t + d];
    __syncthreads();
  }
  if (t == 0) partial[blockIdx.x] = s[0];
}

// block-local exclusive scan + inline prefix of partial[0..bid) -> cursor
__global__ __launch_bounds__(256) void scanC2(const unsigned* __restrict__ counts,
                                              const unsigned* __restrict__ partial,
                                              unsigned* __restrict__ cursor)
{
  __shared__ unsigned sp[256];
  __shared__ unsigned s[256];
  const int t = threadIdx.x;
  const int b = blockIdx.x;
  sp[t] = (t < 196 && t < b) ? partial[t] : 0u;
  __syncthreads();
  for (int d = 128; d > 0; d >>= 1){
    if (t < d) sp[t] += sp[t + d];
    __syncthreads();
  }
  const unsigned boff = sp[0];
  const int idx = b * 256 + t;
  unsigned v = (idx < NN) ? counts[idx] : 0u;
  s[t] = v;
  __syncthreads();
  for (int d = 1; d < 256; d <<= 1){
    unsigned u = (t >= d) ? s[t - d] : 0u;
    __syncthreads();
    s[t] += u;
    __syncthreads();
  }
  if (idx < NN) cursor[idx] = boff + s[t] - v;
}

// combo: blocks 0..3124 = slot assignment; blocks 3125..3906 = node_pre (MFMA).
__global__ __launch_bounds__(256) void combo_k(
    const int* __restrict__ src, const int* __restrict__ dst,
    unsigned* __restrict__ cursor, u64* __restrict__ sdbuf,
    const float* __restrict__ nf,
    const _Float16* __restrict__ rw1h, const float* __restrict__ rb1,
    const _Float16* __restrict__ rw2h, const float* __restrict__ rb2,
    const _Float16* __restrict__ l1wh, const float* __restrict__ l1b,
    const _Float16* __restrict__ pwh, const _Float16* __restrict__ qwh,
    const float* __restrict__ mb1,
    _Float16* __restrict__ xh, _Float16* __restrict__ Pp, _Float16* __restrict__ Qp,
    float* __restrict__ out)
{
  __shared__ _Float16 sM[64][72];
  __shared__ _Float16 sT[64][72];
  const int b = blockIdx.x;
  const int t = threadIdx.x;

  if (b < 3125){
    int e = b * 256 + t;
    if (e < NE){
      const int d = dst[e];
      unsigned slot = atomicAdd(&cursor[d], 1u);
      sdbuf[slot] = ((u64)(unsigned)d << 32) | (unsigned)src[e];
    }
    return;
  }

  const int lane = t & 63, wv = t >> 6;
  const int l15 = lane & 15, kg = lane >> 4;
  const int n0 = (b - 3125) * 64;

  {
    const int rr = t >> 4, c4 = (t & 15) * 4;
    #pragma unroll
    for (int i = 0; i < 4; ++i){
      int r = rr + i*16, n = n0 + r;
      float4 v = make_float4(0.f,0.f,0.f,0.f);
      if (n < NN) v = *(const float4*)&nf[(size_t)n*64 + c4];
      half4 h; h[0]=(_Float16)v.x; h[1]=(_Float16)v.y; h[2]=(_Float16)v.z; h[3]=(_Float16)v.w;
      *(half4*)&sM[r][c4] = h;
    }
  }
  __syncthreads();

  const int col = wv*16 + l15;

  // GEMM1: tmp = nf@rw1 + rb1 -> sT
  {
    half4 bf[4];
    #pragma unroll
    for (int kt = 0; kt < 4; ++kt) bf[kt] = *(const half4*)&rw1h[col*64 + kt*16 + kg*4];
    const float bias = rb1[col];
    #pragma unroll
    for (int rt = 0; rt < 4; ++rt){
      f32x4 acc = {0.f,0.f,0.f,0.f};
      #pragma unroll
      for (int kt = 0; kt < 4; ++kt){
        const half4 af = *(const half4*)&sM[rt*16 + l15][kt*16 + kg*4];
        acc = __builtin_amdgcn_mfma_f32_16x16x16f16(af, bf[kt], acc, 0, 0, 0);
      }
      #pragma unroll
      for (int reg = 0; reg < 4; ++reg)
        sT[rt*16 + kg*4 + reg][col] = (_Float16)(acc[reg] + bias);
    }
  }
  __syncthreads();

  // GEMM2: x = tmp@rw2 + rb2 + nf -> xh (f16) and sM (in-place, lane-owned)
  {
    half4 bf[4];
    #pragma unroll
    for (int kt = 0; kt < 4; ++kt) bf[kt] = *(const half4*)&rw2h[col*64 + kt*16 + kg*4];
    const float bias = rb2[col];
    #pragma unroll
    for (int rt = 0; rt < 4; ++rt){
      f32x4 acc = {0.f,0.f,0.f,0.f};
      #pragma unroll
      for (int kt = 0; kt < 4; ++kt){
        const half4 af = *(const half4*)&sT[rt*16 + l15][kt*16 + kg*4];
        acc = __builtin_amdgcn_mfma_f32_16x16x16f16(af, bf[kt], acc, 0, 0, 0);
      }
      #pragma unroll
      for (int reg = 0; reg < 4; ++reg){
        const int row = rt*16 + kg*4 + reg;
        const float xv = acc[reg] + bias + (float)sM[row][col];
        const _Float16 xvh = (_Float16)xv;
        const int n = n0 + row;
        if (n < NN) xh[(size_t)n*64 + col] = xvh;
        sM[row][col] = xvh;
      }
    }
  }
  __syncthreads();

  // GEMM3: x1 = x@l1w + l1b -> out
  {
    half4 bf[4];
    #pragma unroll
    for (int kt = 0; kt < 4; ++kt) bf[kt] = *(const half4*)&l1wh[col*64 + kt*16 + kg*4];
    const float bias = l1b[col];
    #pragma unroll
    for (int rt = 0; rt < 4; ++rt){
      f32x4 acc = {0.f,0.f,0.f,0.f};
      #pragma unroll
      for (int kt = 0; kt < 4; ++kt){
        const half4 af = *(const half4*)&sM[rt*16 + l15][kt*16 + kg*4];
        acc = __builtin_amdgcn_mfma_f32_16x16x16f16(af, bf[kt], acc, 0, 0, 0);
      }
      #pragma unroll
      for (int reg = 0; reg < 4; ++reg){
        const int row = rt*16 + kg*4 + reg;
        const int n = n0 + row;
        if (n < NN) out[(size_t)n*64 + col] = acc[reg] + bias;
      }
    }
  }

  // GEMM4/5: P = x@W1top + b1 (folded), Q = x@W1bot; k-permuted stores
  #pragma unroll
  for (int g = 0; g < 2; ++g){
    const _Float16* WH = g ? qwh : pwh;
    _Float16* dstp = g ? Qp : Pp;
    #pragma unroll
    for (int h = 0; h < 2; ++h){
      const int ct = h*4 + wv;
      const int colp = ct*16 + l15;
      half4 bf[4];
      #pragma unroll
      for (int kt = 0; kt < 4; ++kt) bf[kt] = *(const half4*)&WH[colp*64 + kt*16 + kg*4];
      const float bias = g ? 0.f : mb1[colp];
      const int kgc = l15 >> 2, jj = l15 & 3;
      const int pos = kgc*32 + ct*4 + jj;   // kperm(pos) == colp
      #pragma unroll
      for (int rt = 0; rt < 4; ++rt){
        f32x4 acc = {0.f,0.f,0.f,0.f};
        #pragma unroll
        for (int kt = 0; kt < 4; ++kt){
          const half4 af = *(const half4*)&sM[rt*16 + l15][kt*16 + kg*4];
          acc = __builtin_amdgcn_mfma_f32_16x16x16f16(af, bf[kt], acc, 0, 0, 0);
        }
        #pragma unroll
        for (int reg = 0; reg < 4; ++reg){
          const int row = rt*16 + kg*4 + reg;
          const int n = n0 + row;
          if (n < NN) dstp[(size_t)n*128 + pos] = (_Float16)(acc[reg] + bias);
        }
      }
    }
  }
}

// Edge MLP v10: v8 structure (4 tiles/block, 1-tile prefetch, B hoisted) with
// split COMPUTE/REDUCE halves -> LDS 27.6KB -> 5 blocks/CU (was 4).
__global__ __launch_bounds__(256) void edge_mlp10(
    const u64* __restrict__ sd,
    const _Float16* __restrict__ Pp, const _Float16* __restrict__ Qp,
    const _Float16* __restrict__ w2t, const _Float16* __restrict__ w2gh,
    const float* __restrict__ b2,
    float* __restrict__ nfoc1, unsigned* __restrict__ nfoc2)
{
  __shared__ _Float16 sA[64][136];     // mid' (k-permuted)
  __shared__ _Float16 sOutHh[64][72];  // one 64-col half of o+bias
  __shared__ float sK[2][64];
  __shared__ int   sD[2][64];
  const int t = threadIdx.x;
  const int lane = t & 63, wv = t >> 6;
  const int r  = lane & 15;
  const int kg = lane >> 4;
  const int row0 = wv * 16;
  const int base = blockIdx.x * 256;

  // hoist B-fragments: pass0 tile wv (cols 0-63), pass1 tile wv+4 (cols 64-127)
  half4 bf0[8], bf1[8];
  half8 wgr[4];
  float bias0, bias1;
  {
    const int col0 = wv*16 + r, col1 = (wv+4)*16 + r;
    bias0 = b2[1 + col0]; bias1 = b2[1 + col1];
    const _Float16* w0p = &w2t[(size_t)col0*128 + kg*32];
    const _Float16* w1p = &w2t[(size_t)col1*128 + kg*32];
    #pragma unroll
    for (int kt = 0; kt < 8; ++kt){
      bf0[kt] = *(const half4*)&w0p[kt*4];
      bf1[kt] = *(const half4*)&w1p[kt*4];
    }
    #pragma unroll
    for (int i = 0; i < 4; ++i) wgr[i] = *(const half8*)&w2gh[kg*32 + i*8];
  }
  const float gb = b2[0];

#define LOADRAW(PH, QH, SS, DD, TILE) { \
    const u64 sdv = sd[base + (TILE)*64 + row0 + r]; \
    SS = (int)(unsigned)(sdv & 0xffffffffu); \
    DD = (int)(unsigned)(sdv >> 32); \
    const _Float16* pr = &Pp[(size_t)SS * 128 + kg*32]; \
    const _Float16* qr = &Qp[(size_t)DD * 128 + kg*32]; \
    PH[0] = *(const half8*)&pr[0];  PH[1] = *(const half8*)&pr[8]; \
    PH[2] = *(const half8*)&pr[16]; PH[3] = *(const half8*)&pr[24]; \
    QH[0] = *(const half8*)&qr[0];  QH[1] = *(const half8*)&qr[8]; \
    QH[2] = *(const half8*)&qr[16]; QH[3] = *(const half8*)&qr[24]; }

#define PROCESS(PH, QH, DD, BUF) { \
    if (kg == 0) sD[BUF][row0 + r] = DD; \
    float gp = 0.f; \
    _Pragma("unroll") \
    for (int i = 0; i < 4; ++i){ \
      half8 mv = PH[i] + QH[i]; \
      const half8 m2 = mv * (_Float16)0.2f; \
      mv = __builtin_elementwise_max(mv, m2); \
      _Pragma("unroll") \
      for (int j = 0; j < 8; ++j) \
        gp = fmaf((float)mv[j], (float)wgr[i][j], gp); \
      *(half8*)&sA[row0 + r][kg*32 + i*8] = mv; \
    } \
    gp += __shfl_xor(gp, 16); \
    gp += __shfl_xor(gp, 32); \
    if (kg == 0) sK[BUF][row0 + r] = 1.f / (1.f + expf(-(gp + gb))); }

// wave wv computes one 16-col tile (buffer col = wv*16 + r) for all 64 rows
#define COMPUTE_HALF(BF, BIAS) { \
    _Pragma("unroll") \
    for (int rt = 0; rt < 4; ++rt){ \
      half4 af[8]; \
      const _Float16* ar = &sA[rt*16 + r][kg*32]; \
      _Pragma("unroll") \
      for (int kt = 0; kt < 8; ++kt) af[kt] = *(const half4*)&ar[kt*4]; \
      f32x4 a0 = {0.f,0.f,0.f,0.f}; \
      _Pragma("unroll") \
      for (int kt = 0; kt < 8; ++kt) \
        a0 = __builtin_amdgcn_mfma_f32_16x16x16f16(af[kt], BF[kt], a0, 0, 0, 0); \
      _Pragma("unroll") \
      for (int reg = 0; reg < 4; ++reg){ \
        const int row = rt*16 + kg*4 + reg; \
        sOutHh[row][wv*16 + r] = (_Float16)(a0[reg] + BIAS); \
      } \
    } }

// 4 threads/col x 16-row windows over 64 dst-sorted rows
#define REDUCE_SUM(BUF) { \
    const int c = t & 63; \
    const int rbeg = (t >> 6) * 16; \
    float acc = 0.f; \
    int curd = sD[BUF][rbeg]; \
    _Pragma("unroll 4") \
    for (int rw = rbeg; rw < rbeg + 16; ++rw){ \
      acc += (float)sOutHh[rw][c] * sK[BUF][rw]; \
      const bool last = (rw == rbeg + 15) || (sD[BUF][rw + 1] != curd); \
      if (last){ \
        unsafeAtomicAdd(&nfoc1[(size_t)curd*64 + c], acc); \
        acc = 0.f; \
        if (rw < rbeg + 15) curd = sD[BUF][rw + 1]; \
      } \
    } }

#define REDUCE_MAX(BUF) { \
    const int c = t & 63; \
    const int rbeg = (t >> 6) * 16; \
    float acc = -1e30f; \
    int curd = sD[BUF][rbeg]; \
    _Pragma("unroll 4") \
    for (int rw = rbeg; rw < rbeg + 16; ++rw){ \
      acc = fmaxf(acc, (float)sOutHh[rw][c] * sK[BUF][rw]); \
      const bool last = (rw == rbeg + 15) || (sD[BUF][rw + 1] != curd); \
      if (last){ \
        atomicMax(&nfoc2[(size_t)curd*64 + c], fenc(acc)); \
        acc = -1e30f; \
        if (rw < rbeg + 15) curd = sD[BUF][rw + 1]; \
      } \
    } }

#define TILE_BODY(BUF) \
    __syncthreads(); \
    COMPUTE_HALF(bf0, bias0); \
    __syncthreads(); \
    REDUCE_SUM(BUF); \
    __syncthreads(); \
    COMPUTE_HALF(bf1, bias1); \
    __syncthreads(); \
    REDUCE_MAX(BUF);

  int s0, d0, s1, d1;
  half8 ph0[4], qh0[4], ph1[4], qh1[4];

  LOADRAW(ph0, qh0, s0, d0, 0);

  // tile 0
  LOADRAW(ph1, qh1, s1, d1, 1);
  PROCESS(ph0, qh0, d0, 0);
  TILE_BODY(0);

  // tile 1
  LOADRAW(ph0, qh0, s0, d0, 2);
  PROCESS(ph1, qh1, d1, 1);
  TILE_BODY(1);

  // tile 2
  LOADRAW(ph1, qh1, s1, d1, 3);
  PROCESS(ph0, qh0, d0, 0);
  TILE_BODY(0);

  // tile 3
  PROCESS(ph1, qh1, d1, 1);
  TILE_BODY(1);

#undef LOADRAW
#undef PROCESS
#undef COMPUTE_HALF
#undef REDUCE_SUM
#undef REDUCE_MAX
#undef TILE_BODY
}

// Node-side post (MFMA, fused weight): out += concat(x,nfoc1,nfoc2) @ W' + fb
__global__ __launch_bounds__(256) void node_post_m(
    const _Float16* __restrict__ xh, const float* __restrict__ nfoc1,
    const unsigned* __restrict__ nfoc2, const unsigned* __restrict__ counts,
    const _Float16* __restrict__ fwh, const float* __restrict__ fb,
    float* __restrict__ out)
{
  __shared__ _Float16 sC[64][200];
  const int t = threadIdx.x;
  const int lane = t & 63, wv = t >> 6;
  const int l15 = lane & 15, kg = lane >> 4;
  const int n0 = blockIdx.x * 64;

  {
    const int rr = t >> 4, c4 = (t & 15) * 4;
    #pragma unroll
    for (int i = 0; i < 4; ++i){
      int r = rr + i*16, n = n0 + r;
      half4 xv = {};
      float4 f1 = make_float4(0,0,0,0);
      uint4 f2 = make_uint4(0,0,0,0);
      bool has = false;
      if (n < NN){
        xv = *(const half4*)&xh[(size_t)n*64 + c4];
        f1 = *(const float4*)&nfoc1[(size_t)n*64 + c4];
        f2 = *(const uint4*)&nfoc2[(size_t)n*64 + c4];
        has = counts[n] > 0u;
      }
      *(half4*)&sC[r][c4] = xv;
      half4 h1; h1[0]=(_Float16)f1.x; h1[1]=(_Float16)f1.y; h1[2]=(_Float16)f1.z; h1[3]=(_Float16)f1.w;
      *(half4*)&sC[r][64 + c4] = h1;
      half4 h2;
      h2[0] = has ? (_Float16)fdec(f2.x) : (_Float16)0.f;
      h2[1] = has ? (_Float16)fdec(f2.y) : (_Float16)0.f;
      h2[2] = has ? (_Float16)fdec(f2.z) : (_Float16)0.f;
      h2[3] = has ? (_Float16)fdec(f2.w) : (_Float16)0.f;
      *(half4*)&sC[r][128 + c4] = h2;
    }
  }
  __syncthreads();

  const int col = wv*16 + l15;
  half4 bf[12];
  #pragma unroll
  for (int kt = 0; kt < 12; ++kt) bf[kt] = *(const half4*)&fwh[col*192 + kt*16 + kg*4];
  const float bias = fb[col];

  #pragma unroll
  for (int rt = 0; rt < 4; ++rt){
    f32x4 acc = {0.f,0.f,0.f,0.f};
    #pragma unroll
    for (int kt = 0; kt < 12; ++kt){
      const half4 af = *(const half4*)&sC[rt*16 + l15][kt*16 + kg*4];
      acc = __builtin_amdgcn_mfma_f32_16x16x16f16(af, bf[kt], acc, 0, 0, 0);
    }
    #pragma unroll
    for (int reg = 0; reg < 4; ++reg){
      const int row = rt*16 + kg*4 + reg;
      const int n = n0 + row;
      if (n < NN) out[(size_t)n*64 + col] += acc[reg] + bias;
    }
  }
}

extern "C" void kernel_launch(void* const* d_in, const int* in_sizes, int n_in,
                              void* d_out, int out_size, void* d_ws, size_t ws_size,
                              hipStream_t stream)
{
  const float* nf   = (const float*)d_in[0];
  const int*   src  = (const int*)d_in[1];
  const int*   dst  = (const int*)d_in[2];
  const float* rw1  = (const float*)d_in[3];
  const float* rb1  = (const float*)d_in[4];
  const float* rw2  = (const float*)d_in[5];
  const float* rb2  = (const float*)d_in[6];
  const float* l1w  = (const float*)d_in[7];
  const float* l1b  = (const float*)d_in[8];
  const float* l2w  = (const float*)d_in[9];
  const float* l2b  = (const float*)d_in[10];
  const float* mw1  = (const float*)d_in[11];
  const float* mb1  = (const float*)d_in[12];
  const float* mw2  = (const float*)d_in[13];
  const float* mb2  = (const float*)d_in[14];
  const float* redw = (const float*)d_in[15];
  const float* redb = (const float*)d_in[16];

  float* ws = (float*)d_ws;
  _Float16*  xh     = (_Float16*)(ws + XHOFF);
  _Float16*  P      = (_Float16*)(ws + POFF);
  _Float16*  Q      = (_Float16*)(ws + QOFF);
  float*     nfoc1  = ws + N1OFF;
  unsigned*  nfoc2  = (unsigned*)(ws + N2OFF);
  _Float16*  w2t    = (_Float16*)(ws + W2TOFF);
  _Float16*  w2gh   = (_Float16*)(ws + WGHOFF);
  _Float16*  rw1h   = (_Float16*)(ws + RW1HOFF);
  _Float16*  rw2h   = (_Float16*)(ws + RW2HOFF);
  _Float16*  l1wh   = (_Float16*)(ws + L1WHOFF);
  _Float16*  pwh    = (_Float16*)(ws + PWHOFF);
  _Float16*  qwh    = (_Float16*)(ws + QWHOFF);
  unsigned*  counts = (unsigned*)(ws + CNTOFF);
  unsigned*  cursor = (unsigned*)(ws + CUROFF);
  unsigned*  partial= (unsigned*)(ws + PARTOFF);
  u64*       sdbuf  = (u64*)(ws + SDOFF);
  _Float16*  fwh    = (_Float16*)(ws + FWOFF);
  float*     fb     = ws + FBOFF;
  float*     out    = (float*)d_out;

  hipMemsetAsync(counts, 0, NN * sizeof(unsigned), stream);
  hipLaunchKernelGGL(prep_k, dim3(1748 + 3125), dim3(256), 0, stream,
                     mw2, rw1, rw2, l1w, mw1, redw, redb, l2w, l2b,
                     w2t, w2gh, rw1h, rw2h, l1wh, pwh, qwh, fwh, fb,
                     (uint4*)nfoc1, dst, counts);
  hipLaunchKernelGGL(scanA, dim3(196), dim3(256), 0, stream, counts, partial);
  hipLaunchKernelGGL(scanC2, dim3(196), dim3(256), 0, stream, counts, partial, cursor);
  hipLaunchKernelGGL(combo_k, dim3(3125 + 782), dim3(256), 0, stream,
                     src, dst, cursor, sdbuf,
                     nf, rw1h, rb1, rw2h, rb2, l1wh, l1b, pwh, qwh, mb1,
                     xh, P, Q, out);
  hipLaunchKernelGGL(edge_mlp10, dim3(3125), dim3(256), 0, stream,
                     sdbuf, P, Q, w2t, w2gh, mb2, nfoc1, nfoc2);
  hipLaunchKernelGGL(node_post_m, dim3(782), dim3(256), 0, stream,
                     xh, nfoc1, nfoc2, counts, fwh, fb, out);
}